// Round 16
// baseline (118.428 us; speedup 1.0000x reference)
//
#include <hip/hip_runtime.h>

// DSAttention round 16 = r15 (persistent, CH=4, fixed-shift softmax) with:
//  (1) prep kernel: K -> f16 Kh[bh][s][e]; K B-frags loaded DIRECTLY from
//      global into registers (h8, coalesced), double-buffered one tile ahead.
//      The barrier's implicit vmcnt(0) drain completes kf_next exactly when
//      it's needed -> full-iteration latency hiding, zero K LDS traffic.
//  (2) one-pass PV (Pb 32 rows/wave): V B-frags read once, shared by both
//      q-frags. LDS reads/wave-iter: 28 -> 12 b128. LDS 36864 B.

typedef _Float16 h8 __attribute__((ext_vector_type(8)));
typedef _Float16 h2 __attribute__((ext_vector_type(2)));
typedef float f32x4 __attribute__((ext_vector_type(4)));

constexpr int Bc = 2, Lc = 2048, Hc = 8, Ec = 64, Sc = 2048;
constexpr int QTL = 128;              // q rows per work item
constexpr int NQT = Lc / QTL;         // 16 q-tiles
constexpr int KT = 64;                // keys per tile
constexpr int LDK = 72;               // LDS row stride (halfs)
constexpr int NBH = Bc * Hc;          // 16
constexpr float SCALE = 0.125f;
constexpr float LOG2E = 1.44269504088896340736f;

__device__ __forceinline__ h2 pk2(float x, float y) {
  return __builtin_bit_cast(h2, __builtin_amdgcn_cvt_pkrtz(x, y));
}
template <int CTRL>
__device__ __forceinline__ float dpp_f(float x) {
  int r = __builtin_amdgcn_update_dpp(0, __builtin_bit_cast(int, x), CTRL, 0xF, 0xF, true);
  return __builtin_bit_cast(float, r);
}

// ---------------- prep: fp32 K -> f16 Kh[bh][s][e] ----------------
__global__ __launch_bounds__(256)
void dsattn_prep(const float* __restrict__ Kg, _Float16* __restrict__ Kh) {
  const int bh = (int)blockIdx.y;
  const int b = bh >> 3, h = bh & 7;
  const int s0 = (int)blockIdx.x * 64;
  const int tid = (int)threadIdx.x;
  const int srow = tid >> 2, sec = (tid & 3) << 4;
  const float* kp = Kg + (((size_t)b * Sc + s0 + srow) * Hc + h) * Ec + sec;
  float4 c0 = ((const float4*)kp)[0], c1 = ((const float4*)kp)[1];
  float4 c2 = ((const float4*)kp)[2], c3 = ((const float4*)kp)[3];
  union { h8 v; h2 c[4]; } w0, w1;
  w0.c[0] = pk2(c0.x, c0.y); w0.c[1] = pk2(c0.z, c0.w);
  w0.c[2] = pk2(c1.x, c1.y); w0.c[3] = pk2(c1.z, c1.w);
  w1.c[0] = pk2(c2.x, c2.y); w1.c[1] = pk2(c2.z, c2.w);
  w1.c[2] = pk2(c3.x, c3.y); w1.c[3] = pk2(c3.z, c3.w);
  _Float16* ko = Kh + ((size_t)bh * Sc + s0 + srow) * Ec + sec;
  *(h8*)ko = w0.v;
  *(h8*)(ko + 8) = w1.v;
}

// CH_IT = kt-tiles per chunk; EPB = work entries per (b,h); NIT = total items
template <int CH_IT, int EPB, int NIT>
__global__ __launch_bounds__(256, 2)
void dsattn_fwd(const float* __restrict__ Qg, const _Float16* __restrict__ Kh,
                const float* __restrict__ Vg, const float* __restrict__ taug,
                const float* __restrict__ deltag, float* __restrict__ Og,
                _Float16* __restrict__ Opart, float* __restrict__ Lpart) {
  __shared__ __align__(16) _Float16 Vt[2][Ec * LDK];   // 18432 B
  __shared__ __align__(16) _Float16 Pb[4][32 * LDK];   // 18432 B -> 36864 total

  const int tid = threadIdx.x;
  const int wave = tid >> 6, lane = tid & 63;
  const int quad = lane >> 4, l16 = lane & 15;
  const int vrp = ((tid >> 3) + 4 * (tid & 7)) & 31;
  const int ve8 = (tid & 7) << 3;
  _Float16* pb = &Pb[wave][0];
  const int lo = l16 & 1;
  const int pbase = (lo ? 32 : 0) + (l16 & ~1);

  h8 onesf;
#pragma unroll
  for (int j = 0; j < 8; ++j) onesf[j] = (_Float16)1.0f;

  for (int wid = (int)blockIdx.x; wid < NIT; wid += (int)gridDim.x) {
    const int bh = wid & (NBH - 1);
    const int e = wid >> 4;
    int qt = NQT - 1, c0 = 0, pre_e = 0;
    {
      int ee = e, acc = 0;
#pragma unroll
      for (int q = NQT - 1; q >= 0; --q) {
        const int n = (2 * q + 1 + CH_IT) / CH_IT;    // nch(q)
        if (ee < n) { qt = q; c0 = ee; pre_e = EPB - acc - n; break; }
        ee -= n; acc += n;
      }
    }
    const int ntiles = 2 * qt + 2;
    const int nch = (ntiles + CH_IT - 1) / CH_IT;
    const int ktBeg = c0 * CH_IT;
    const int ktEnd = min(ktBeg + CH_IT - 1, ntiles - 1);
    const int q0 = qt * QTL;
    const int b = bh >> 3, h = bh & 7;
    const float ct = taug[b] * (SCALE * LOG2E);
    const _Float16* kbh = Kh + (size_t)bh * Sc * Ec;

    // ---- Q A-fragments ----
    h8 qfrag[2][2];
#pragma unroll
    for (int f = 0; f < 2; ++f)
#pragma unroll
      for (int kk = 0; kk < 2; ++kk) {
        const float* qp = Qg + (((size_t)b * Lc + q0 + 32 * wave + 16 * f + l16) * Hc + h) * Ec
                         + quad * 8 + kk * 32;
        const float4* p = (const float4*)qp;
        union { h8 v; h2 c[4]; } u;
        float4 a0 = p[0], a1 = p[1];
        u.c[0] = pk2(a0.x, a0.y); u.c[1] = pk2(a0.z, a0.w);
        u.c[2] = pk2(a1.x, a1.y); u.c[3] = pk2(a1.z, a1.w);
        qfrag[f][kk] = u.v;
      }

    f32x4 Oacc[2][4], Osum[2];
#pragma unroll
    for (int f = 0; f < 2; ++f) {
#pragma unroll
      for (int nt = 0; nt < 4; ++nt) Oacc[f][nt] = (f32x4){0.f, 0.f, 0.f, 0.f};
      Osum[f] = (f32x4){0.f, 0.f, 0.f, 0.f};
    }

    float dcur[4];
    h8 kf[4][2];                     // current tile's K B-frags (registers)

    __syncthreads();   // previous item's LDS reads complete before restaging

    // ---- prologue: V tile ktBeg -> Vt[0]; K frags + delta direct ----
    {
      const int kb = ktBeg * KT;
#pragma unroll
      for (int nt = 0; nt < 4; ++nt)
#pragma unroll
        for (int kk = 0; kk < 2; ++kk)
          kf[nt][kk] = *(const h8*)&kbh[(size_t)(kb + nt * 16 + l16) * Ec + quad * 8 + kk * 32];
      const float* vp0 = Vg + (((size_t)b * Sc + kb + 2 * vrp) * Hc + h) * Ec + ve8;
      const float* vp1 = vp0 + Hc * Ec;
      float4 r00 = ((const float4*)vp0)[0], r01 = ((const float4*)vp0)[1];
      float4 r10 = ((const float4*)vp1)[0], r11 = ((const float4*)vp1)[1];
#pragma unroll
      for (int nt = 0; nt < 4; ++nt)
        dcur[nt] = deltag[(size_t)b * Sc + kb + nt * 16 + l16] * (SCALE * LOG2E);
      const float e0[8] = {r00.x, r00.y, r00.z, r00.w, r01.x, r01.y, r01.z, r01.w};
      const float e1[8] = {r10.x, r10.y, r10.z, r10.w, r11.x, r11.y, r11.z, r11.w};
#pragma unroll
      for (int j = 0; j < 8; ++j)
        *(h2*)&Vt[0][(ve8 + j) * LDK + 2 * vrp] = pk2(e0[j], e1[j]);
    }

    for (int kt = ktBeg; kt <= ktEnd; ++kt) {
      const int cur = (kt - ktBeg) & 1;
      const bool pf = (kt < ktEnd);
      const int kbase = kt * KT;

      __syncthreads();   // Vt[cur] ready; prev-iter kf_next loads drained here

      // ---- prefetch kt+1 AFTER the barrier (V->regs, K->kf_next regs) ----
      float4 vn00, vn01, vn10, vn11;
      float dn[4];
      h8 kfn[4][2];
      if (pf) {
        const int nb = (kt + 1) * KT;
#pragma unroll
        for (int nt = 0; nt < 4; ++nt)
#pragma unroll
          for (int kk = 0; kk < 2; ++kk)
            kfn[nt][kk] = *(const h8*)&kbh[(size_t)(nb + nt * 16 + l16) * Ec + quad * 8 + kk * 32];
        const float* vp0 = Vg + (((size_t)b * Sc + nb + 2 * vrp) * Hc + h) * Ec + ve8;
        const float* vp1 = vp0 + Hc * Ec;
        vn00 = ((const float4*)vp0)[0]; vn01 = ((const float4*)vp0)[1];
        vn10 = ((const float4*)vp1)[0]; vn11 = ((const float4*)vp1)[1];
#pragma unroll
        for (int nt = 0; nt < 4; ++nt)
          dn[nt] = deltag[(size_t)b * Sc + nb + nt * 16 + l16];
      }

      // wave-uniform: skip tiles fully above this wave's rows
      const int wtop = q0 + 32 * wave + 31;
      if (kbase <= wtop) {
        // ---- S = Q.K^T : K frags from registers, zero LDS ----
        f32x4 Sacc[2][4];
#pragma unroll
        for (int f = 0; f < 2; ++f)
#pragma unroll
          for (int nt = 0; nt < 4; ++nt) Sacc[f][nt] = (f32x4){0.f, 0.f, 0.f, 0.f};
#pragma unroll
        for (int kk = 0; kk < 2; ++kk)
#pragma unroll
          for (int f = 0; f < 2; ++f)
#pragma unroll
            for (int nt = 0; nt < 4; ++nt)
              Sacc[f][nt] = __builtin_amdgcn_mfma_f32_16x16x32_f16(qfrag[f][kk], kf[nt][kk], Sacc[f][nt], 0, 0, 0);

        // ---- fixed-shift softmax, both frags -> P rows 16f+quad*4+r ----
#pragma unroll
        for (int f = 0; f < 2; ++f) {
          const int fr0 = q0 + 32 * wave + 16 * f;
          float sv[4][4];
#pragma unroll
          for (int nt = 0; nt < 4; ++nt)
#pragma unroll
            for (int r = 0; r < 4; ++r)
              sv[nt][r] = Sacc[f][nt][r] * ct + dcur[nt];
          if (kbase + 63 > fr0) {
#pragma unroll
            for (int nt = 0; nt < 4; ++nt) {
              const int key = kbase + nt * 16 + l16;
#pragma unroll
              for (int r = 0; r < 4; ++r)
                if (key > fr0 + quad * 4 + r) sv[nt][r] = -1e30f;
            }
          }
#pragma unroll
          for (int nt = 0; nt < 4; ++nt)
#pragma unroll
            for (int r = 0; r < 4; ++r)
              sv[nt][r] = __builtin_amdgcn_exp2f(sv[nt][r]);   // bounded
#pragma unroll
          for (int r = 0; r < 4; ++r) {
            float o0 = dpp_f<0xB1>(sv[0][r]);
            float o1 = dpp_f<0xB1>(sv[1][r]);
            float o2 = dpp_f<0xB1>(sv[2][r]);
            float o3 = dpp_f<0xB1>(sv[3][r]);
            h2 d0 = lo ? pk2(o2, sv[2][r]) : pk2(sv[0][r], o0);
            h2 d1 = lo ? pk2(o3, sv[3][r]) : pk2(sv[1][r], o1);
            _Float16* pp = &pb[(16 * f + (quad << 2) + r) * LDK + pbase];
            *(h2*)pp = d0;
            *(h2*)(pp + 16) = d1;
          }
        }
        asm volatile("s_waitcnt lgkmcnt(0)" ::: "memory");  // wave-local P RAW

        h8 af[2][2];
#pragma unroll
        for (int f = 0; f < 2; ++f)
#pragma unroll
          for (int kk = 0; kk < 2; ++kk)
            af[f][kk] = *(const h8*)&pb[(16 * f + l16) * LDK + quad * 8 + kk * 32];

        // ---- one-pass PV: V frags read once, shared by both q-frags ----
#pragma unroll
        for (int kk = 0; kk < 2; ++kk) {
#pragma unroll
          for (int nt = 0; nt < 4; ++nt) {
            h8 vf = *(const h8*)&Vt[cur][(nt * 16 + l16) * LDK + quad * 8 + kk * 32];
#pragma unroll
            for (int f = 0; f < 2; ++f)
              Oacc[f][nt] = __builtin_amdgcn_mfma_f32_16x16x32_f16(af[f][kk], vf, Oacc[f][nt], 0, 0, 0);
          }
#pragma unroll
          for (int f = 0; f < 2; ++f)
            Osum[f] = __builtin_amdgcn_mfma_f32_16x16x32_f16(af[f][kk], onesf, Osum[f], 0, 0, 0);
        }
      }

      // ---- stage prefetched V; adopt kf_next ----
      if (pf) {
        _Float16* vtn = &Vt[cur ^ 1][0];
        const float e0[8] = {vn00.x, vn00.y, vn00.z, vn00.w, vn01.x, vn01.y, vn01.z, vn01.w};
        const float e1[8] = {vn10.x, vn10.y, vn10.z, vn10.w, vn11.x, vn11.y, vn11.z, vn11.w};
#pragma unroll
        for (int j = 0; j < 8; ++j)
          *(h2*)&vtn[(ve8 + j) * LDK + 2 * vrp] = pk2(e0[j], e1[j]);
#pragma unroll
        for (int nt = 0; nt < 4; ++nt) {
          dcur[nt] = dn[nt] * (SCALE * LOG2E);
#pragma unroll
          for (int kk = 0; kk < 2; ++kk) kf[nt][kk] = kfn[nt][kk];
        }
      }
    }

    // ---- epilogue ----
    if (nch == 1) {
#pragma unroll
      for (int f = 0; f < 2; ++f)
#pragma unroll
        for (int r = 0; r < 4; ++r) {
          const int qrow = q0 + 32 * wave + 16 * f + (quad << 2) + r;
          const float inv = 1.0f / Osum[f][r];
          float* op = Og + (((size_t)b * Lc + qrow) * Hc + h) * Ec;
#pragma unroll
          for (int nt = 0; nt < 4; ++nt) op[nt * 16 + l16] = Oacc[f][nt][r] * inv;
        }
    } else {
      const int en = bh * EPB + pre_e + c0;
      _Float16* op = Opart + (size_t)en * (QTL * Ec);
#pragma unroll
      for (int f = 0; f < 2; ++f)
#pragma unroll
        for (int r = 0; r < 4; ++r) {
          const int row = 32 * wave + 16 * f + (quad << 2) + r;
#pragma unroll
          for (int nt = 0; nt < 4; ++nt)
            op[row * Ec + nt * 16 + l16] = (_Float16)Oacc[f][nt][r];
          if (l16 == 0) Lpart[en * QTL + row] = Osum[f][r];
        }
    }
  }
}

template <int CH_IT, int EPB>
__global__ __launch_bounds__(256, 4)
void dsattn_comb(const _Float16* __restrict__ Opart, const float* __restrict__ Lpart,
                 float* __restrict__ Og) {
  const int qt = (CH_IT / 2) + ((int)blockIdx.x >> 2);  // multi-chunk q-tiles
  const int slab = (int)blockIdx.x & 3;                 // 32-row slab
  const int bh = (int)blockIdx.y;
  const int b = bh >> 3, h = bh & 7;
  const int nch = (2 * qt + 1 + CH_IT) / CH_IT;         // 2..8
  int pre_e = 0;
#pragma unroll
  for (int q = 0; q < NQT; ++q)
    if (q < qt) pre_e += (2 * q + 1 + CH_IT) / CH_IT;
  const int e0 = bh * EPB + pre_e;

  const int row = slab * 32 + ((int)threadIdx.x >> 3);  // 0..127
  const int col = ((int)threadIdx.x & 7) << 3;          // 8 cols per thread

  float acc[8];
#pragma unroll
  for (int i = 0; i < 8; ++i) acc[i] = 0.f;
  float l = 0.f;
  for (int c = 0; c < nch; ++c) {
    l += Lpart[(e0 + c) * QTL + row];
    h8 v = *(const h8*)(Opart + (size_t)(e0 + c) * (QTL * Ec) + row * Ec + col);
#pragma unroll
    for (int i = 0; i < 8; ++i) acc[i] += (float)v[i];
  }
  const float inv = 1.0f / l;
  float* out = Og + (((size_t)b * Lc + qt * QTL + row) * Hc + h) * Ec + col;
  float4 o0, o1;
  o0.x = acc[0] * inv; o0.y = acc[1] * inv; o0.z = acc[2] * inv; o0.w = acc[3] * inv;
  o1.x = acc[4] * inv; o1.y = acc[5] * inv; o1.z = acc[6] * inv; o1.w = acc[7] * inv;
  ((float4*)out)[0] = o0;
  ((float4*)out)[1] = o1;
}

extern "C" void kernel_launch(void* const* d_in, const int* in_sizes, int n_in,
                              void* d_out, int out_size, void* d_ws, size_t ws_size,
                              hipStream_t stream) {
  const float* Q = (const float*)d_in[0];
  const float* K = (const float*)d_in[1];
  const float* V = (const float*)d_in[2];
  const float* tau = (const float*)d_in[3];
  const float* delta = (const float*)d_in[4];
  float* O = (float*)d_out;

  constexpr int CH = 4;                          // kt-tiles per chunk (256 keys)
  constexpr int EPB = 72;                        // sum of nch over 16 q-tiles
  constexpr int TOT_E = Bc * Hc * EPB;           // 1152 work items
  constexpr int PERS = 768;                      // 3 blocks/CU x 256 CUs
  constexpr size_t KVH = (size_t)NBH * Sc * Ec;  // halfs in Kh

  _Float16* Kh = (_Float16*)d_ws;
  _Float16* Opart = Kh + KVH;
  float* Lpart = (float*)(Opart + (size_t)TOT_E * QTL * Ec);
  const size_t need = KVH * 2 + (size_t)TOT_E * QTL * Ec * 2
                    + (size_t)TOT_E * QTL * 4;

  dsattn_prep<<<dim3(Sc / 64, NBH), 256, 0, stream>>>(K, Kh);

  if (ws_size >= need) {
    dsattn_fwd<CH, EPB, TOT_E><<<dim3(PERS), 256, 0, stream>>>(
        Q, Kh, V, tau, delta, O, Opart, Lpart);
    dim3 g2((NQT - CH / 2) * 4, Bc * Hc);  // 4 row-slabs per multi-chunk q-tile
    dsattn_comb<CH, EPB><<<g2, 256, 0, stream>>>(Opart, Lpart, O);
  } else {
    // monolithic fallback: one item per (qt,bh); needs only Kh in ws
    dsattn_fwd<32, NQT, NQT * NBH><<<dim3(NQT * NBH), 256, 0, stream>>>(
        Q, Kh, V, tau, delta, O, nullptr, nullptr);
  }
}

// Round 17
// 110.074 us; speedup vs baseline: 1.0759x; 1.0759x over previous
//
#include <hip/hip_runtime.h>

// DSAttention round 17 = REVERT to r15 verbatim (best measured: 109.3 us).
// r15 = persistent 768-block grid, CH=4 split-K, two-pass PV (LDS 46080B),
// FIXED-SHIFT softmax (P = exp2(s), no max machinery — scores bounded),
// f16 partials, plain-sum combine.
// r16's K-direct-from-global variant improved every work counter (VALU,
// FETCH, conflicts) yet regressed wall time — confirming the kernel is
// latency-chain-bound, not work-bound; r15 is the plateau configuration.

typedef _Float16 h8 __attribute__((ext_vector_type(8)));
typedef _Float16 h2 __attribute__((ext_vector_type(2)));
typedef float f32x4 __attribute__((ext_vector_type(4)));

constexpr int Bc = 2, Lc = 2048, Hc = 8, Ec = 64, Sc = 2048;
constexpr int QTL = 128;              // q rows per work item
constexpr int NQT = Lc / QTL;         // 16 q-tiles
constexpr int KT = 64;                // keys per staged tile
constexpr int LDK = 72;               // LDS row stride (halfs)
constexpr int NBH = Bc * Hc;          // 16
constexpr float SCALE = 0.125f;
constexpr float LOG2E = 1.44269504088896340736f;

__device__ __forceinline__ h2 pk2(float x, float y) {
  return __builtin_bit_cast(h2, __builtin_amdgcn_cvt_pkrtz(x, y));
}
template <int CTRL>
__device__ __forceinline__ float dpp_f(float x) {
  int r = __builtin_amdgcn_update_dpp(0, __builtin_bit_cast(int, x), CTRL, 0xF, 0xF, true);
  return __builtin_bit_cast(float, r);
}

// CH_IT = kt-tiles per chunk; EPB = work entries per (b,h); NIT = total items
template <int CH_IT, int EPB, int NIT>
__global__ __launch_bounds__(256, 2)
void dsattn_fwd(const float* __restrict__ Qg, const float* __restrict__ Kg,
                const float* __restrict__ Vg, const float* __restrict__ taug,
                const float* __restrict__ deltag, float* __restrict__ Og,
                _Float16* __restrict__ Opart, float* __restrict__ Lpart) {
  __shared__ __align__(16) _Float16 Ks[2][KT * LDK];   // 18432 B
  __shared__ __align__(16) _Float16 Vt[2][Ec * LDK];   // 18432 B
  __shared__ __align__(16) _Float16 Pb[4][16 * LDK];   //  9216 B -> 46080 total

  const int tid = threadIdx.x;
  const int wave = tid >> 6, lane = tid & 63;
  const int quad = lane >> 4, l16 = lane & 15;
  const int srow = tid >> 2;
  const int sec = (tid & 3) << 4;
  const int vrp = ((tid >> 3) + 4 * (tid & 7)) & 31;
  const int ve8 = (tid & 7) << 3;
  _Float16* pb = &Pb[wave][0];
  const int lo = l16 & 1;
  const int pbase = (lo ? 32 : 0) + (l16 & ~1);

  h8 onesf;
#pragma unroll
  for (int j = 0; j < 8; ++j) onesf[j] = (_Float16)1.0f;

  // ---- persistent loop over flattened work items ----
  for (int wid = (int)blockIdx.x; wid < NIT; wid += (int)gridDim.x) {
    const int bh = wid & (NBH - 1);
    const int e = wid >> 4;              // [0, EPB)
    int qt = NQT - 1, c0 = 0, pre_e = 0;
    {
      int ee = e, acc = 0;
#pragma unroll
      for (int q = NQT - 1; q >= 0; --q) {
        const int n = (2 * q + 1 + CH_IT) / CH_IT;    // nch(q)
        if (ee < n) { qt = q; c0 = ee; pre_e = EPB - acc - n; break; }
        ee -= n; acc += n;
      }
    }
    const int ntiles = 2 * qt + 2;
    const int nch = (ntiles + CH_IT - 1) / CH_IT;
    const int ktBeg = c0 * CH_IT;
    const int ktEnd = min(ktBeg + CH_IT - 1, ntiles - 1);
    const int q0 = qt * QTL;
    const int b = bh >> 3, h = bh & 7;
    const float ct = taug[b] * (SCALE * LOG2E);

    // ---- Q A-fragments ----
    h8 qfrag[2][2];
#pragma unroll
    for (int f = 0; f < 2; ++f)
#pragma unroll
      for (int kk = 0; kk < 2; ++kk) {
        const float* qp = Qg + (((size_t)b * Lc + q0 + 32 * wave + 16 * f + l16) * Hc + h) * Ec
                         + quad * 8 + kk * 32;
        const float4* p = (const float4*)qp;
        union { h8 v; h2 c[4]; } u;
        float4 a0 = p[0], a1 = p[1];
        u.c[0] = pk2(a0.x, a0.y); u.c[1] = pk2(a0.z, a0.w);
        u.c[2] = pk2(a1.x, a1.y); u.c[3] = pk2(a1.z, a1.w);
        qfrag[f][kk] = u.v;
      }

    f32x4 Oacc[2][4], Osum[2];
#pragma unroll
    for (int f = 0; f < 2; ++f) {
#pragma unroll
      for (int nt = 0; nt < 4; ++nt) Oacc[f][nt] = (f32x4){0.f, 0.f, 0.f, 0.f};
      Osum[f] = (f32x4){0.f, 0.f, 0.f, 0.f};
    }

    float dcur[4];

    __syncthreads();   // previous item's LDS reads complete before restaging

    // ---- prologue: stage tile ktBeg into buffer 0 ----
    {
      const int kb = ktBeg * KT;
      const float* kp = Kg + (((size_t)b * Sc + kb + srow) * Hc + h) * Ec + sec;
      float4 c0v = ((const float4*)kp)[0], c1v = ((const float4*)kp)[1];
      float4 c2v = ((const float4*)kp)[2], c3v = ((const float4*)kp)[3];
      const float* vp0 = Vg + (((size_t)b * Sc + kb + 2 * vrp) * Hc + h) * Ec + ve8;
      const float* vp1 = vp0 + Hc * Ec;
      float4 r00 = ((const float4*)vp0)[0], r01 = ((const float4*)vp0)[1];
      float4 r10 = ((const float4*)vp1)[0], r11 = ((const float4*)vp1)[1];
#pragma unroll
      for (int nt = 0; nt < 4; ++nt)
        dcur[nt] = deltag[(size_t)b * Sc + kb + nt * 16 + l16] * (SCALE * LOG2E);
      union { h8 v; h2 c[4]; } w0, w1;
      w0.c[0] = pk2(c0v.x, c0v.y); w0.c[1] = pk2(c0v.z, c0v.w);
      w0.c[2] = pk2(c1v.x, c1v.y); w0.c[3] = pk2(c1v.z, c1v.w);
      w1.c[0] = pk2(c2v.x, c2v.y); w1.c[1] = pk2(c2v.z, c2v.w);
      w1.c[2] = pk2(c3v.x, c3v.y); w1.c[3] = pk2(c3v.z, c3v.w);
      *(h8*)&Ks[0][srow * LDK + sec] = w0.v;
      *(h8*)&Ks[0][srow * LDK + sec + 8] = w1.v;
      const float e0[8] = {r00.x, r00.y, r00.z, r00.w, r01.x, r01.y, r01.z, r01.w};
      const float e1[8] = {r10.x, r10.y, r10.z, r10.w, r11.x, r11.y, r11.z, r11.w};
#pragma unroll
      for (int j = 0; j < 8; ++j)
        *(h2*)&Vt[0][(ve8 + j) * LDK + 2 * vrp] = pk2(e0[j], e1[j]);
    }

    for (int kt = ktBeg; kt <= ktEnd; ++kt) {
      const int cur = (kt - ktBeg) & 1;
      const bool pf = (kt < ktEnd);
      const int kbase = kt * KT;

      __syncthreads();   // buffer cur ready; vmcnt naturally drained

      // ---- prefetch kt+1 AFTER the barrier ----
      float4 kn0, kn1, kn2, kn3, vn00, vn01, vn10, vn11;
      float dn[4];
      if (pf) {
        const int nb = (kt + 1) * KT;
        const float* kp = Kg + (((size_t)b * Sc + nb + srow) * Hc + h) * Ec + sec;
        kn0 = ((const float4*)kp)[0]; kn1 = ((const float4*)kp)[1];
        kn2 = ((const float4*)kp)[2]; kn3 = ((const float4*)kp)[3];
        const float* vp0 = Vg + (((size_t)b * Sc + nb + 2 * vrp) * Hc + h) * Ec + ve8;
        const float* vp1 = vp0 + Hc * Ec;
        vn00 = ((const float4*)vp0)[0]; vn01 = ((const float4*)vp0)[1];
        vn10 = ((const float4*)vp1)[0]; vn11 = ((const float4*)vp1)[1];
#pragma unroll
        for (int nt = 0; nt < 4; ++nt)
          dn[nt] = deltag[(size_t)b * Sc + nb + nt * 16 + l16];
      }

      // wave-uniform: skip tiles fully above this wave's rows
      const int wtop = q0 + 32 * wave + 31;
      if (kbase <= wtop) {
        // ---- S = Q.K^T ----
        f32x4 Sacc[2][4];
#pragma unroll
        for (int f = 0; f < 2; ++f)
#pragma unroll
          for (int nt = 0; nt < 4; ++nt) Sacc[f][nt] = (f32x4){0.f, 0.f, 0.f, 0.f};
#pragma unroll
        for (int kk = 0; kk < 2; ++kk) {
          h8 bf[4];
#pragma unroll
          for (int nt = 0; nt < 4; ++nt)
            bf[nt] = *(const h8*)&Ks[cur][(nt * 16 + l16) * LDK + quad * 8 + kk * 32];
#pragma unroll
          for (int f = 0; f < 2; ++f)
#pragma unroll
            for (int nt = 0; nt < 4; ++nt)
              Sacc[f][nt] = __builtin_amdgcn_mfma_f32_16x16x32_f16(qfrag[f][kk], bf[nt], Sacc[f][nt], 0, 0, 0);
        }

        // ---- two passes: P(f) = exp2(s) -> LDS -> PV(f); NO max machinery ----
#pragma unroll
        for (int f = 0; f < 2; ++f) {
          const int fr0 = q0 + 32 * wave + 16 * f;
          float sv[4][4];
#pragma unroll
          for (int nt = 0; nt < 4; ++nt)
#pragma unroll
            for (int r = 0; r < 4; ++r)
              sv[nt][r] = Sacc[f][nt][r] * ct + dcur[nt];
          if (kbase + 63 > fr0) {
#pragma unroll
            for (int nt = 0; nt < 4; ++nt) {
              const int key = kbase + nt * 16 + l16;
#pragma unroll
              for (int r = 0; r < 4; ++r)
                if (key > fr0 + quad * 4 + r) sv[nt][r] = -1e30f;
            }
          }
#pragma unroll
          for (int nt = 0; nt < 4; ++nt)
#pragma unroll
            for (int r = 0; r < 4; ++r)
              sv[nt][r] = __builtin_amdgcn_exp2f(sv[nt][r]);   // bounded: <= ~6e3

          // P -> LDS rows quad*4+r (DPP xor1 pairing, packed h2 writes)
#pragma unroll
          for (int r = 0; r < 4; ++r) {
            float o0 = dpp_f<0xB1>(sv[0][r]);
            float o1 = dpp_f<0xB1>(sv[1][r]);
            float o2 = dpp_f<0xB1>(sv[2][r]);
            float o3 = dpp_f<0xB1>(sv[3][r]);
            h2 d0 = lo ? pk2(o2, sv[2][r]) : pk2(sv[0][r], o0);
            h2 d1 = lo ? pk2(o3, sv[3][r]) : pk2(sv[1][r], o1);
            _Float16* pp = &pb[((quad << 2) + r) * LDK + pbase];
            *(h2*)pp = d0;
            *(h2*)(pp + 16) = d1;
          }
          asm volatile("s_waitcnt lgkmcnt(0)" ::: "memory");  // wave-local P RAW

          h8 af0 = *(const h8*)&pb[l16 * LDK + quad * 8];
          h8 af1 = *(const h8*)&pb[l16 * LDK + quad * 8 + 32];

#pragma unroll
          for (int nt = 0; nt < 4; ++nt) {
            h8 vf0 = *(const h8*)&Vt[cur][(nt * 16 + l16) * LDK + quad * 8];
            Oacc[f][nt] = __builtin_amdgcn_mfma_f32_16x16x32_f16(af0, vf0, Oacc[f][nt], 0, 0, 0);
            h8 vf1 = *(const h8*)&Vt[cur][(nt * 16 + l16) * LDK + quad * 8 + 32];
            Oacc[f][nt] = __builtin_amdgcn_mfma_f32_16x16x32_f16(af1, vf1, Oacc[f][nt], 0, 0, 0);
          }
          Osum[f] = __builtin_amdgcn_mfma_f32_16x16x32_f16(af0, onesf, Osum[f], 0, 0, 0);
          Osum[f] = __builtin_amdgcn_mfma_f32_16x16x32_f16(af1, onesf, Osum[f], 0, 0, 0);
        }
      }

      // ---- write prefetched tile kt+1 into the other buffer ----
      if (pf) {
        _Float16* ksn = &Ks[cur ^ 1][0];
        _Float16* vtn = &Vt[cur ^ 1][0];
        union { h8 v; h2 c[4]; } w0, w1;
        w0.c[0] = pk2(kn0.x, kn0.y); w0.c[1] = pk2(kn0.z, kn0.w);
        w0.c[2] = pk2(kn1.x, kn1.y); w0.c[3] = pk2(kn1.z, kn1.w);
        w1.c[0] = pk2(kn2.x, kn2.y); w1.c[1] = pk2(kn2.z, kn2.w);
        w1.c[2] = pk2(kn3.x, kn3.y); w1.c[3] = pk2(kn3.z, kn3.w);
        *(h8*)&ksn[srow * LDK + sec] = w0.v;
        *(h8*)&ksn[srow * LDK + sec + 8] = w1.v;
        const float e0[8] = {vn00.x, vn00.y, vn00.z, vn00.w, vn01.x, vn01.y, vn01.z, vn01.w};
        const float e1[8] = {vn10.x, vn10.y, vn10.z, vn10.w, vn11.x, vn11.y, vn11.z, vn11.w};
#pragma unroll
        for (int j = 0; j < 8; ++j)
          *(h2*)&vtn[(ve8 + j) * LDK + 2 * vrp] = pk2(e0[j], e1[j]);
#pragma unroll
        for (int nt = 0; nt < 4; ++nt) dcur[nt] = dn[nt] * (SCALE * LOG2E);
      }
    }

    // ---- epilogue ----
    if (nch == 1) {
#pragma unroll
      for (int f = 0; f < 2; ++f)
#pragma unroll
        for (int r = 0; r < 4; ++r) {
          const int qrow = q0 + 32 * wave + 16 * f + (quad << 2) + r;
          const float inv = 1.0f / Osum[f][r];
          float* op = Og + (((size_t)b * Lc + qrow) * Hc + h) * Ec;
#pragma unroll
          for (int nt = 0; nt < 4; ++nt) op[nt * 16 + l16] = Oacc[f][nt][r] * inv;
        }
    } else {
      const int en = bh * EPB + pre_e + c0;
      _Float16* op = Opart + (size_t)en * (QTL * Ec);
#pragma unroll
      for (int f = 0; f < 2; ++f)
#pragma unroll
        for (int r = 0; r < 4; ++r) {
          const int row = 32 * wave + 16 * f + (quad << 2) + r;
#pragma unroll
          for (int nt = 0; nt < 4; ++nt)
            op[row * Ec + nt * 16 + l16] = (_Float16)Oacc[f][nt][r];
          if (l16 == 0) Lpart[en * QTL + row] = Osum[f][r];
        }
    }
  }
}

template <int CH_IT, int EPB>
__global__ __launch_bounds__(256, 4)
void dsattn_comb(const _Float16* __restrict__ Opart, const float* __restrict__ Lpart,
                 float* __restrict__ Og) {
  const int qt = (CH_IT / 2) + ((int)blockIdx.x >> 2);  // multi-chunk q-tiles
  const int slab = (int)blockIdx.x & 3;                 // 32-row slab
  const int bh = (int)blockIdx.y;
  const int b = bh >> 3, h = bh & 7;
  const int nch = (2 * qt + 1 + CH_IT) / CH_IT;         // 2..8
  int pre_e = 0;
#pragma unroll
  for (int q = 0; q < NQT; ++q)
    if (q < qt) pre_e += (2 * q + 1 + CH_IT) / CH_IT;
  const int e0 = bh * EPB + pre_e;

  const int row = slab * 32 + ((int)threadIdx.x >> 3);  // 0..127
  const int col = ((int)threadIdx.x & 7) << 3;          // 8 cols per thread

  float acc[8];
#pragma unroll
  for (int i = 0; i < 8; ++i) acc[i] = 0.f;
  float l = 0.f;
  for (int c = 0; c < nch; ++c) {
    l += Lpart[(e0 + c) * QTL + row];
    h8 v = *(const h8*)(Opart + (size_t)(e0 + c) * (QTL * Ec) + row * Ec + col);
#pragma unroll
    for (int i = 0; i < 8; ++i) acc[i] += (float)v[i];
  }
  const float inv = 1.0f / l;
  float* out = Og + (((size_t)b * Lc + qt * QTL + row) * Hc + h) * Ec + col;
  float4 o0, o1;
  o0.x = acc[0] * inv; o0.y = acc[1] * inv; o0.z = acc[2] * inv; o0.w = acc[3] * inv;
  o1.x = acc[4] * inv; o1.y = acc[5] * inv; o1.z = acc[6] * inv; o1.w = acc[7] * inv;
  ((float4*)out)[0] = o0;
  ((float4*)out)[1] = o1;
}

extern "C" void kernel_launch(void* const* d_in, const int* in_sizes, int n_in,
                              void* d_out, int out_size, void* d_ws, size_t ws_size,
                              hipStream_t stream) {
  const float* Q = (const float*)d_in[0];
  const float* K = (const float*)d_in[1];
  const float* V = (const float*)d_in[2];
  const float* tau = (const float*)d_in[3];
  const float* delta = (const float*)d_in[4];
  float* O = (float*)d_out;

  constexpr int CH = 4;                    // kt-tiles per chunk (256 keys)
  constexpr int EPB = 72;                  // sum of nch over 16 q-tiles
  constexpr int TOT_E = Bc * Hc * EPB;     // 1152 work items
  constexpr int PERS = 768;                // 3 blocks/CU x 256 CUs
  const size_t need = (size_t)TOT_E * QTL * Ec * 2 + (size_t)TOT_E * QTL * 4;

  if (ws_size >= need) {
    _Float16* Opart = (_Float16*)d_ws;
    float* Lpart = (float*)(Opart + (size_t)TOT_E * QTL * Ec);
    dsattn_fwd<CH, EPB, TOT_E><<<dim3(PERS), 256, 0, stream>>>(
        Q, K, V, tau, delta, O, Opart, Lpart);
    dim3 g2((NQT - CH / 2) * 4, Bc * Hc);  // 4 row-slabs per multi-chunk q-tile
    dsattn_comb<CH, EPB><<<g2, 256, 0, stream>>>(Opart, Lpart, O);
  } else {
    // monolithic fallback: one item per (qt,bh), no workspace
    dsattn_fwd<32, NQT, NQT * NBH><<<dim3(NQT * NBH), 256, 0, stream>>>(
        Q, K, V, tau, delta, O, nullptr, nullptr);
  }
}